// Round 1
// baseline (978.231 us; speedup 1.0000x reference)
//
#include <hip/hip_runtime.h>

#define NB 16
#define C  256
#define H  64
#define W  64
#define E  32     // c/8
#define F  768    // 3c
#define HW 4096   // h*w
#define K5 2048   // E*W

// ---------------------------------------------------------------------------
// Kernel A: fused t1 (einsum over h) -> t3 (9x9 depthwise) -> t4 (5x1 grouped)
// One block per (n, group-of-4-channels). 256 threads.
// ---------------------------------------------------------------------------
__global__ __launch_bounds__(256) void k_t4(const float* __restrict__ x,
                                            const float* __restrict__ p1,
                                            const float* __restrict__ p3,
                                            const float* __restrict__ p4,
                                            float* __restrict__ t4) {
  const int n  = blockIdx.x >> 6;
  const int g  = blockIdx.x & 63;
  const int c0 = g * 4;
  const int tid = threadIdx.x;
  const int w  = tid & 63;
  const int e0 = tid >> 6;  // 0..3

  __shared__ __align__(16) float xs[H][W];       // 16 KB
  __shared__ __align__(16) float t1s[E][W];      // 8 KB
  __shared__ __align__(16) float t3s[4][E][W];   // 32 KB

  for (int q = 0; q < 4; ++q) {
    const int ch = c0 + q;
    const float* xp = x + ((size_t)(n * C + ch)) * (H * W);
    __syncthreads();  // previous iteration done with xs/t1s
#pragma unroll
    for (int i = 0; i < 4; ++i)
      ((float4*)xs)[tid + 256 * i] = ((const float4*)xp)[tid + 256 * i];
    __syncthreads();
    // t1: t1s[e][w] = sum_h xs[h][w] * p1[h*E+e]; thread owns w, e = e0+4i
    {
      float acc[8];
#pragma unroll
      for (int i = 0; i < 8; ++i) acc[i] = 0.f;
      for (int h = 0; h < H; ++h) {
        float xv = xs[h][w];
        const float* p1h = p1 + h * E;
#pragma unroll
        for (int i = 0; i < 8; ++i) acc[i] += xv * p1h[e0 + 4 * i];
      }
#pragma unroll
      for (int i = 0; i < 8; ++i) t1s[e0 + 4 * i][w] = acc[i];
    }
    __syncthreads();
    // t3: 9x9 depthwise conv, pad 4 both dims
    {
      const float* w3 = p3 + ch * 81;
#pragma unroll
      for (int i8 = 0; i8 < 8; ++i8) {
        int e = e0 + 4 * i8;
        float acc = 0.f;
        for (int i = 0; i < 9; ++i) {
          int ee = e + i - 4;
          if (ee < 0 || ee >= E) continue;
#pragma unroll
          for (int j = 0; j < 9; ++j) {
            int ww = w + j - 4;
            if (ww >= 0 && ww < W) acc += t1s[ee][ww] * w3[i * 9 + j];
          }
        }
        t3s[q][e][w] = acc;
      }
    }
  }
  __syncthreads();
  // t4: grouped (5,1) conv along e, pad 2; group = this block's 4 channels
  for (int q = 0; q < 4; ++q) {
    const int ch = c0 + q;
    const float* w4 = p4 + ch * 20;  // [ci][u]
    float* outp = t4 + ((size_t)(n * C + ch)) * (E * W);
#pragma unroll
    for (int i8 = 0; i8 < 8; ++i8) {
      int e = e0 + 4 * i8;
      float acc = 0.f;
#pragma unroll
      for (int ci = 0; ci < 4; ++ci) {
#pragma unroll
        for (int u = 0; u < 5; ++u) {
          int ee = e + u - 2;
          if (ee >= 0 && ee < E) acc += t3s[ci][ee][w] * w4[ci * 5 + u];
        }
      }
      outp[e * W + w] = acc;
    }
  }
}

// ---------------------------------------------------------------------------
// Kernel B: t5 = t4[4096][2048] x p5[2048][768].  64x64 tile, 4x4 micro.
// ---------------------------------------------------------------------------
__global__ __launch_bounds__(256) void k_t5(const float* __restrict__ A,
                                            const float* __restrict__ B,
                                            float* __restrict__ Cm) {
  const int col0 = blockIdx.x * 64;  // 12 tiles
  const int row0 = blockIdx.y * 64;  // 64 tiles
  const int tid = threadIdx.x;
  const int tx = tid & 15, ty = tid >> 4;

  __shared__ __align__(16) float As[16][68];
  __shared__ __align__(16) float Bs[16][68];

  float acc[4][4];
#pragma unroll
  for (int i = 0; i < 4; ++i)
#pragma unroll
    for (int j = 0; j < 4; ++j) acc[i][j] = 0.f;

  for (int k0 = 0; k0 < K5; k0 += 16) {
#pragma unroll
    for (int l = 0; l < 4; ++l) {
      int idx = tid + 256 * l;
      int m = idx >> 4, k = idx & 15;
      As[k][m] = A[(size_t)(row0 + m) * K5 + k0 + k];
    }
#pragma unroll
    for (int l = 0; l < 4; ++l) {
      int idx = tid + 256 * l;
      int k = idx >> 6, nn = idx & 63;
      Bs[k][nn] = B[(size_t)(k0 + k) * F + col0 + nn];
    }
    __syncthreads();
#pragma unroll
    for (int k = 0; k < 16; ++k) {
      float4 a = *(const float4*)&As[k][ty * 4];
      float4 b = *(const float4*)&Bs[k][tx * 4];
      float av[4] = {a.x, a.y, a.z, a.w};
      float bv[4] = {b.x, b.y, b.z, b.w};
#pragma unroll
      for (int i = 0; i < 4; ++i)
#pragma unroll
        for (int j = 0; j < 4; ++j) acc[i][j] += av[i] * bv[j];
    }
    __syncthreads();
  }
#pragma unroll
  for (int i = 0; i < 4; ++i) {
    float4 v = make_float4(acc[i][0], acc[i][1], acc[i][2], acc[i][3]);
    *(float4*)&Cm[(size_t)(row0 + ty * 4 + i) * F + col0 + tx * 4] = v;
  }
}

// ---------------------------------------------------------------------------
// Kernel C: t6 = 3-tap depthwise conv along f (pad 1)
// ---------------------------------------------------------------------------
__global__ __launch_bounds__(256) void k_t6(const float* __restrict__ t5,
                                            const float* __restrict__ p6,
                                            float* __restrict__ t6) {
  int idx = blockIdx.x * 256 + threadIdx.x;
  if (idx >= NB * C * F) return;
  int f = idx % F;
  int nc = idx / F;
  int c = nc % C;
  const float* row = t5 + (size_t)nc * F;
  const float* wt = p6 + c * 3;
  float acc = row[f] * wt[1];
  if (f > 0) acc += row[f - 1] * wt[0];
  if (f < F - 1) acc += row[f + 1] * wt[2];
  t6[idx] = acc;
}

// ---------------------------------------------------------------------------
// Kernel D: out[n][c][p] = (1/sqrt(768)) * sum_f t6[n][c][f] * B[f][p]
// where B[3*c2+k][h*64+w] = x[n][c2][h+k-1][w] (zero-padded), read on the fly.
// 128x128 tile, 8x8 micro, per-n batch.
// ---------------------------------------------------------------------------
__global__ __launch_bounds__(256) void k_out(const float* __restrict__ t6,
                                             const float* __restrict__ x,
                                             float* __restrict__ outp) {
  const int tn = blockIdx.x;  // 0..31  (p tiles of 128 -> h pair tn*2, tn*2+1)
  const int tm = blockIdx.y;  // 0..1   (c tiles of 128)
  const int n  = blockIdx.z;  // 0..15
  const int row0 = tm * 128;
  const int tid = threadIdx.x;
  const int tx = tid & 15, ty = tid >> 4;

  __shared__ __align__(16) float As[16][132];
  __shared__ __align__(16) float Bs[16][132];

  const float* Arow = t6 + (size_t)n * C * F;
  const float* xn = x + (size_t)n * C * HW;

  float acc[8][8];
#pragma unroll
  for (int i = 0; i < 8; ++i)
#pragma unroll
    for (int j = 0; j < 8; ++j) acc[i][j] = 0.f;

  for (int k0 = 0; k0 < F; k0 += 16) {
#pragma unroll
    for (int l = 0; l < 8; ++l) {
      int idx = tid + 256 * l;
      int m = idx >> 4, k = idx & 15;
      As[k][m] = Arow[(size_t)(row0 + m) * F + k0 + k];
    }
#pragma unroll
    for (int l = 0; l < 8; ++l) {
      int idx = tid + 256 * l;
      int k = idx >> 7, nn = idx & 127;
      int f = k0 + k;
      int c2 = f / 3;
      int kk = f - c2 * 3;
      int hh = tn * 2 + (nn >> 6) + kk - 1;
      float v = 0.f;
      if (hh >= 0 && hh < H) v = xn[((size_t)c2 * H + hh) * W + (nn & 63)];
      Bs[k][nn] = v;
    }
    __syncthreads();
#pragma unroll
    for (int k = 0; k < 16; ++k) {
      float a[8], b[8];
      *(float4*)&a[0] = *(const float4*)&As[k][ty * 8];
      *(float4*)&a[4] = *(const float4*)&As[k][ty * 8 + 4];
      *(float4*)&b[0] = *(const float4*)&Bs[k][tx * 8];
      *(float4*)&b[4] = *(const float4*)&Bs[k][tx * 8 + 4];
#pragma unroll
      for (int i = 0; i < 8; ++i)
#pragma unroll
        for (int j = 0; j < 8; ++j) acc[i][j] += a[i] * b[j];
    }
    __syncthreads();
  }
  const float scale = 0.03608439182435161f;  // 1/sqrt(768)
#pragma unroll
  for (int i = 0; i < 8; ++i) {
    int c = row0 + ty * 8 + i;
    float* op = outp + ((size_t)(n * C + c)) * HW + tn * 128 + tx * 8;
    float4 v0 = make_float4(acc[i][0] * scale, acc[i][1] * scale,
                            acc[i][2] * scale, acc[i][3] * scale);
    float4 v1 = make_float4(acc[i][4] * scale, acc[i][5] * scale,
                            acc[i][6] * scale, acc[i][7] * scale);
    *(float4*)&op[0] = v0;
    *(float4*)&op[4] = v1;
  }
}

extern "C" void kernel_launch(void* const* d_in, const int* in_sizes, int n_in,
                              void* d_out, int out_size, void* d_ws, size_t ws_size,
                              hipStream_t stream) {
  (void)in_sizes; (void)n_in; (void)out_size; (void)ws_size;
  const float* x  = (const float*)d_in[0];
  const float* p1 = (const float*)d_in[1];
  const float* p3 = (const float*)d_in[2];
  const float* p4 = (const float*)d_in[3];
  const float* p5 = (const float*)d_in[4];
  const float* p6 = (const float*)d_in[5];
  float* out = (float*)d_out;

  char* ws = (char*)d_ws;
  float* t4 = (float*)ws;                                   // 4096*2048 f32 = 33.5 MB
  float* t5 = (float*)(ws + (size_t)4096 * 2048 * 4);       // 4096*768  f32 = 12.6 MB
  float* t6 = (float*)ws;                                   // reuse t4 region after k_t5

  k_t4<<<dim3(NB * 64), 256, 0, stream>>>(x, p1, p3, p4, t4);
  k_t5<<<dim3(12, 64), 256, 0, stream>>>(t4, p5, t5);
  k_t6<<<dim3((NB * C * F + 255) / 256), 256, 0, stream>>>(t5, p6, t6);
  k_out<<<dim3(32, 2, 16), 256, 0, stream>>>(t6, x, out);
}

// Round 2
// 377.513 us; speedup vs baseline: 2.5913x; 2.5913x over previous
//
#include <hip/hip_runtime.h>

#define NB 16
#define C  256
#define H  64
#define W  64
#define E  32
#define F  768
#define HW 4096
#define K5 2048
#define XROWS 4224   // 64 pad + 4096 + 64 pad

typedef __attribute__((ext_vector_type(4))) float f32x4;
typedef __attribute__((ext_vector_type(8))) short s16x8;

__device__ inline unsigned short to_bf16(float f) {
  union { float f; unsigned u; } v; v.f = f;
  unsigned u = v.u;
  u += 0x7fff + ((u >> 16) & 1);
  return (unsigned short)(u >> 16);
}

__device__ inline void gload16(const void* g, void* l) {
  __builtin_amdgcn_global_load_lds((const __attribute__((address_space(1))) unsigned int*)g,
                                   (__attribute__((address_space(3))) unsigned int*)l, 16, 0, 0);
}

// ---------------------------------------------------------------------------
// Kernel A: fused t1 -> t3 (9x9 dw) -> t4 (5x1 grouped), output bf16
// ---------------------------------------------------------------------------
__global__ __launch_bounds__(256) void k_t4(const float* __restrict__ x,
                                            const float* __restrict__ p1,
                                            const float* __restrict__ p3,
                                            const float* __restrict__ p4,
                                            unsigned short* __restrict__ t4b) {
  const int n  = blockIdx.x >> 6;
  const int g  = blockIdx.x & 63;
  const int c0 = g * 4;
  const int tid = threadIdx.x;
  const int w  = tid & 63;
  const int e0 = tid >> 6;

  __shared__ __align__(16) float xs[H][W];
  __shared__ __align__(16) float t1s[E][W];
  __shared__ __align__(16) float t3s[4][E][W];

  for (int q = 0; q < 4; ++q) {
    const int ch = c0 + q;
    const float* xp = x + ((size_t)(n * C + ch)) * (H * W);
    __syncthreads();
#pragma unroll
    for (int i = 0; i < 4; ++i)
      ((float4*)xs)[tid + 256 * i] = ((const float4*)xp)[tid + 256 * i];
    __syncthreads();
    {
      float acc[8];
#pragma unroll
      for (int i = 0; i < 8; ++i) acc[i] = 0.f;
      for (int h = 0; h < H; ++h) {
        float xv = xs[h][w];
        const float* p1h = p1 + h * E;
#pragma unroll
        for (int i = 0; i < 8; ++i) acc[i] += xv * p1h[e0 + 4 * i];
      }
#pragma unroll
      for (int i = 0; i < 8; ++i) t1s[e0 + 4 * i][w] = acc[i];
    }
    __syncthreads();
    {
      const float* w3 = p3 + ch * 81;
#pragma unroll
      for (int i8 = 0; i8 < 8; ++i8) {
        int e = e0 + 4 * i8;
        float acc = 0.f;
        for (int i = 0; i < 9; ++i) {
          int ee = e + i - 4;
          if (ee < 0 || ee >= E) continue;
#pragma unroll
          for (int j = 0; j < 9; ++j) {
            int ww = w + j - 4;
            if (ww >= 0 && ww < W) acc += t1s[ee][ww] * w3[i * 9 + j];
          }
        }
        t3s[q][e][w] = acc;
      }
    }
  }
  __syncthreads();
  for (int q = 0; q < 4; ++q) {
    const int ch = c0 + q;
    const float* w4 = p4 + ch * 20;
    unsigned short* outp = t4b + ((size_t)(n * C + ch)) * (E * W);
#pragma unroll
    for (int i8 = 0; i8 < 8; ++i8) {
      int e = e0 + 4 * i8;
      float acc = 0.f;
#pragma unroll
      for (int ci = 0; ci < 4; ++ci) {
#pragma unroll
        for (int u = 0; u < 5; ++u) {
          int ee = e + u - 2;
          if (ee >= 0 && ee < E) acc += t3s[ci][ee][w] * w4[ci * 5 + u];
        }
      }
      outp[e * W + w] = to_bf16(acc);
    }
  }
}

// ---------------------------------------------------------------------------
// p5 [2048][768] f32 -> p5t [768][2048] bf16 (transpose + convert)
// ---------------------------------------------------------------------------
__global__ __launch_bounds__(256) void k_p5t(const float* __restrict__ p5,
                                             unsigned short* __restrict__ p5t) {
  const int f0 = blockIdx.x * 64;
  const int k0 = blockIdx.y * 64;
  const int tid = threadIdx.x;
  __shared__ __align__(16) unsigned short ls[64][264];
  int fl = tid & 63, k4 = tid >> 6;
  for (int i = 0; i < 16; ++i) {
    int kl = k4 * 16 + i;
    ls[fl][kl] = to_bf16(p5[(size_t)(k0 + kl) * F + f0 + fl]);
  }
  __syncthreads();
#pragma unroll
  for (int j = 0; j < 2; ++j) {
    int chunk = tid + 256 * j;
    int row = chunk >> 3, slot = chunk & 7;
    *(uint4*)(p5t + (size_t)(f0 + row) * K5 + k0 + slot * 8) = *(const uint4*)&ls[row][slot * 8];
  }
}

// ---------------------------------------------------------------------------
// x [n][c][h][w] f32 -> xt [n][64 + h*64+w + 64][c] bf16, zero pads
// ---------------------------------------------------------------------------
__global__ __launch_bounds__(256) void k_xt(const float* __restrict__ x,
                                            unsigned short* __restrict__ xt) {
  const int hi = blockIdx.x;   // 0..65
  const int n = blockIdx.y;
  const int tid = threadIdx.x;
  unsigned short* dst = xt + ((size_t)n * XROWS + hi * 64) * C;
  if (hi == 0 || hi == 65) {
    uint4 z = make_uint4(0, 0, 0, 0);
    uint4* d4 = (uint4*)dst;
#pragma unroll
    for (int i = 0; i < 8; ++i) d4[tid + 256 * i] = z;
    return;
  }
  const int h = hi - 1;
  __shared__ __align__(16) unsigned short ls[64][264];
  const float* xp = x + ((size_t)n * C) * HW + h * 64;
  int w = tid & 63, c4 = tid >> 6;
  for (int i = 0; i < 64; ++i) {
    int c = c4 * 64 + i;
    ls[w][c] = to_bf16(xp[(size_t)c * HW + w]);
  }
  __syncthreads();
#pragma unroll
  for (int j = 0; j < 8; ++j) {
    int chunk = tid + 256 * j;          // 2048 chunks of 16B
    int row = chunk >> 5, slot = chunk & 31;
    *(uint4*)(dst + row * C + slot * 8) = *(const uint4*)&ls[row][slot * 8];
  }
}

// ---------------------------------------------------------------------------
// k_t5m: t5[4096][768] f32 = t4b[4096][2048]bf16 x p5t^T  (MFMA 128x128 tile)
// ---------------------------------------------------------------------------
__global__ __launch_bounds__(256) void k_t5m(const unsigned short* __restrict__ A,
                                             const unsigned short* __restrict__ Bt,
                                             float* __restrict__ Cout) {
  const int n0 = blockIdx.x * 128;
  const int m0 = blockIdx.y * 128;
  const int tid = threadIdx.x;
  const int lane = tid & 63;
  const int wave = tid >> 6;
  const int wm = wave >> 1, wn = wave & 1;
  __shared__ __align__(16) short As[8192];
  __shared__ __align__(16) short Bs[8192];
  f32x4 acc[4][4] = {};
  const int lr = lane >> 3;
  const int ls = lane & 7;

  for (int k0 = 0; k0 < K5; k0 += 64) {
#pragma unroll
    for (int i = 0; i < 4; ++i) {
      int inst = wave * 4 + i;
      int r = inst * 8 + lr;
      int sw = ls ^ (r & 7);
      gload16((const char*)(A + (size_t)(m0 + r) * K5 + k0) + sw * 16,
              (char*)As + inst * 1024);
      gload16((const char*)(Bt + (size_t)(n0 + r) * K5 + k0) + sw * 16,
              (char*)Bs + inst * 1024);
    }
    __syncthreads();
#pragma unroll
    for (int kh = 0; kh < 2; ++kh) {
      s16x8 af[4], bf[4];
#pragma unroll
      for (int mi = 0; mi < 4; ++mi) {
        int row = wm * 64 + mi * 16 + (lane & 15);
        int byte = (row * 128 + kh * 64 + (lane >> 4) * 16) ^ ((row & 7) << 4);
        af[mi] = *(const s16x8*)((const char*)As + byte);
      }
#pragma unroll
      for (int ni = 0; ni < 4; ++ni) {
        int row = wn * 64 + ni * 16 + (lane & 15);
        int byte = (row * 128 + kh * 64 + (lane >> 4) * 16) ^ ((row & 7) << 4);
        bf[ni] = *(const s16x8*)((const char*)Bs + byte);
      }
#pragma unroll
      for (int mi = 0; mi < 4; ++mi)
#pragma unroll
        for (int ni = 0; ni < 4; ++ni)
          acc[mi][ni] = __builtin_amdgcn_mfma_f32_16x16x32_bf16(af[mi], bf[ni], acc[mi][ni], 0, 0, 0);
    }
    __syncthreads();
  }
#pragma unroll
  for (int mi = 0; mi < 4; ++mi) {
    int rbase = m0 + wm * 64 + mi * 16 + (lane >> 4) * 4;
#pragma unroll
    for (int ni = 0; ni < 4; ++ni) {
      int col = n0 + wn * 64 + ni * 16 + (lane & 15);
#pragma unroll
      for (int q = 0; q < 4; ++q)
        Cout[(size_t)(rbase + q) * F + col] = acc[mi][ni][q];
    }
  }
}

// ---------------------------------------------------------------------------
// k_t6: t5 f32 -> 3-tap dw conv (original f order) -> scale -> bf16 in f' order
// f' = kk*256 + c2  (f = 3*c2 + kk)
// ---------------------------------------------------------------------------
__global__ __launch_bounds__(256) void k_t6(const float* __restrict__ t5,
                                            const float* __restrict__ p6,
                                            unsigned short* __restrict__ t6b) {
  int idx = blockIdx.x * 256 + threadIdx.x;
  if (idx >= NB * C * F) return;
  int fp = idx % F;
  int nc = idx / F;
  int c = nc & 255;
  int c2 = fp & 255;
  int kk = fp >> 8;
  int f = 3 * c2 + kk;
  const float* row = t5 + (size_t)nc * F;
  const float* wt = p6 + c * 3;
  float acc = row[f] * wt[1];
  if (f > 0) acc += row[f - 1] * wt[0];
  if (f < F - 1) acc += row[f + 1] * wt[2];
  t6b[idx] = to_bf16(acc * 0.03608439182435161f);
}

// ---------------------------------------------------------------------------
// k_outm: out[n][256][4096] f32 = t6b[n][256][768] x B' (from xt, shifted rows)
// ---------------------------------------------------------------------------
__global__ __launch_bounds__(256) void k_outm(const unsigned short* __restrict__ t6b,
                                              const unsigned short* __restrict__ xt,
                                              float* __restrict__ outp) {
  const int p0 = blockIdx.x * 128;   // 32
  const int m0 = blockIdx.y * 128;   // 2
  const int n  = blockIdx.z;         // 16
  const int tid = threadIdx.x;
  const int lane = tid & 63;
  const int wave = tid >> 6;
  const int wm = wave >> 1, wn = wave & 1;
  __shared__ __align__(16) short As[8192];
  __shared__ __align__(16) short Bs[8192];
  f32x4 acc[4][4] = {};
  const int lr = lane >> 3;
  const int ls = lane & 7;
  const unsigned short* Abase = t6b + (size_t)(n * C) * F;
  const unsigned short* Xbase = xt + (size_t)n * XROWS * C;

  for (int kt = 0; kt < 12; ++kt) {
    int k0 = kt * 64;
    int kk = k0 >> 8;
    int c20 = k0 & 255;
#pragma unroll
    for (int i = 0; i < 4; ++i) {
      int inst = wave * 4 + i;
      int r = inst * 8 + lr;
      int sw = ls ^ (r & 7);
      gload16((const char*)(Abase + (size_t)(m0 + r) * F + k0) + sw * 16,
              (char*)As + inst * 1024);
      gload16((const char*)(Xbase + (size_t)(p0 + r + (kk << 6)) * C + c20) + sw * 16,
              (char*)Bs + inst * 1024);
    }
    __syncthreads();
#pragma unroll
    for (int kh = 0; kh < 2; ++kh) {
      s16x8 af[4], bf[4];
#pragma unroll
      for (int mi = 0; mi < 4; ++mi) {
        int row = wm * 64 + mi * 16 + (lane & 15);
        int byte = (row * 128 + kh * 64 + (lane >> 4) * 16) ^ ((row & 7) << 4);
        af[mi] = *(const s16x8*)((const char*)As + byte);
      }
#pragma unroll
      for (int ni = 0; ni < 4; ++ni) {
        int row = wn * 64 + ni * 16 + (lane & 15);
        int byte = (row * 128 + kh * 64 + (lane >> 4) * 16) ^ ((row & 7) << 4);
        bf[ni] = *(const s16x8*)((const char*)Bs + byte);
      }
#pragma unroll
      for (int mi = 0; mi < 4; ++mi)
#pragma unroll
        for (int ni = 0; ni < 4; ++ni)
          acc[mi][ni] = __builtin_amdgcn_mfma_f32_16x16x32_bf16(af[mi], bf[ni], acc[mi][ni], 0, 0, 0);
    }
    __syncthreads();
  }
  float* obase = outp + (size_t)(n * C) * HW;
#pragma unroll
  for (int mi = 0; mi < 4; ++mi) {
    int rbase = m0 + wm * 64 + mi * 16 + (lane >> 4) * 4;
#pragma unroll
    for (int ni = 0; ni < 4; ++ni) {
      int col = p0 + wn * 64 + ni * 16 + (lane & 15);
#pragma unroll
      for (int q = 0; q < 4; ++q)
        obase[(size_t)(rbase + q) * HW + col] = acc[mi][ni][q];
    }
  }
}

extern "C" void kernel_launch(void* const* d_in, const int* in_sizes, int n_in,
                              void* d_out, int out_size, void* d_ws, size_t ws_size,
                              hipStream_t stream) {
  (void)in_sizes; (void)n_in; (void)out_size; (void)ws_size;
  const float* x  = (const float*)d_in[0];
  const float* p1 = (const float*)d_in[1];
  const float* p3 = (const float*)d_in[2];
  const float* p4 = (const float*)d_in[3];
  const float* p5 = (const float*)d_in[4];
  const float* p6 = (const float*)d_in[5];
  float* out = (float*)d_out;

  char* ws = (char*)d_ws;
  // region [0, 34.6MB): early = {t4b, p5t, t5}; late (after k_t6) = xt
  unsigned short* t4b = (unsigned short*)ws;                          // 16.8 MB
  unsigned short* p5t = (unsigned short*)(ws + 16777216);             //  3.1 MB
  float*          t5  = (float*)(ws + 19922944);                      // 12.6 MB
  unsigned short* xt  = (unsigned short*)ws;                          // 34.6 MB (overlays t4b/p5t/t5)
  unsigned short* t6b = (unsigned short*)(ws + 34603008);             //  6.3 MB

  k_t4 <<<dim3(NB * 64), 256, 0, stream>>>(x, p1, p3, p4, t4b);
  k_p5t<<<dim3(12, 32), 256, 0, stream>>>(p5, p5t);
  k_t5m<<<dim3(6, 32), 256, 0, stream>>>(t4b, p5t, t5);
  k_t6 <<<dim3((NB * C * F + 255) / 256), 256, 0, stream>>>(t5, p6, t6b);
  k_xt <<<dim3(66, NB), 256, 0, stream>>>(x, xt);
  k_outm<<<dim3(32, 2, NB), 256, 0, stream>>>(t6b, xt, out);
}

// Round 3
// 195.990 us; speedup vs baseline: 4.9912x; 1.9262x over previous
//
#include <hip/hip_runtime.h>

#define NB 16
#define C  256
#define H  64
#define W  64
#define E  32
#define F  768
#define HW 4096
#define K5 2048
#define XROWS 4224   // 64 pad + 4096 + 64 pad

typedef __attribute__((ext_vector_type(4))) float f32x4;
typedef __attribute__((ext_vector_type(8))) short s16x8;

__device__ inline unsigned short to_bf16(float f) {
  union { float f; unsigned u; } v; v.f = f;
  unsigned u = v.u;
  u += 0x7fff + ((u >> 16) & 1);
  return (unsigned short)(u >> 16);
}

__device__ inline float from_bf16(unsigned short s) {
  union { unsigned u; float f; } v; v.u = ((unsigned)s) << 16;
  return v.f;
}

__device__ inline void gload16(const void* g, void* l) {
  __builtin_amdgcn_global_load_lds((const __attribute__((address_space(1))) unsigned int*)g,
                                   (__attribute__((address_space(3))) unsigned int*)l, 16, 0, 0);
}

// ---------------------------------------------------------------------------
// Kernel A: fused t1 -> t3 (9x9 dw) -> t4 (5x1 grouped), output bf16.
// Branch-free via zero-padded LDS; vector LDS reads; t3 staged as bf16.
// One block per (n, group-of-4-channels). 256 threads. LDS = 49280 B.
// ---------------------------------------------------------------------------
__global__ __launch_bounds__(256) void k_t4(const float* __restrict__ x,
                                            const float* __restrict__ p1,
                                            const float* __restrict__ p3,
                                            const float* __restrict__ p4,
                                            unsigned short* __restrict__ t4b) {
  const int n  = blockIdx.x >> 6;
  const int g  = blockIdx.x & 63;
  const int c0 = g * 4;
  const int tid = threadIdx.x;

  __shared__ __align__(16) float xs[64][64];              // 16384 B
  __shared__ __align__(16) float t1s[40][76];             // 12160 B  (pad 4 each side)
  __shared__ __align__(16) unsigned short t3s[4][36][72]; // 20736 B  (pad 2 rows each side)

  // zero everything once: pads stay zero, interiors are fully rewritten per q
  {
    float* f = &t1s[0][0];
    for (int i = tid; i < 40 * 76; i += 256) f[i] = 0.f;
    unsigned* u = (unsigned*)&t3s[0][0][0];
    for (int i = tid; i < (4 * 36 * 72) / 2; i += 256) u[i] = 0u;
  }

  const int w  = tid & 63;                                   // t1 mapping
  const int e0 = __builtin_amdgcn_readfirstlane(tid >> 6);   // wave-uniform
  const int e  = tid >> 3;                                   // t3/t4 mapping
  const int wq = tid & 7;
  const int w0 = wq * 8;

  for (int q = 0; q < 4; ++q) {
    const int ch = c0 + q;
    const float* xp = x + ((size_t)(n * C + ch)) * HW;
    __syncthreads();
#pragma unroll
    for (int i = 0; i < 4; ++i)
      ((float4*)xs)[tid + 256 * i] = ((const float4*)xp)[tid + 256 * i];
    __syncthreads();
    // ---- t1: t1s[4+e][4+w] = sum_h xs[h][w] * p1[h][e], e = e0 + 4i
    {
      float acc[8];
#pragma unroll
      for (int i = 0; i < 8; ++i) acc[i] = 0.f;
      for (int h = 0; h < 64; ++h) {
        float xv = xs[h][w];
        const float* p1h = p1 + h * 32 + e0;
#pragma unroll
        for (int i = 0; i < 8; ++i) acc[i] += xv * p1h[4 * i];
      }
#pragma unroll
      for (int i = 0; i < 8; ++i) t1s[4 + e0 + 4 * i][4 + w] = acc[i];
    }
    __syncthreads();
    // ---- t3: 9x9 depthwise, branch-free, 16-float register window per row
    {
      const float* w3 = p3 + ch * 81;
      float o[8];
#pragma unroll
      for (int k = 0; k < 8; ++k) o[k] = 0.f;
#pragma unroll
      for (int i = 0; i < 9; ++i) {
        float win[16];
        *(float4*)&win[0]  = *(const float4*)&t1s[e + i][w0];
        *(float4*)&win[4]  = *(const float4*)&t1s[e + i][w0 + 4];
        *(float4*)&win[8]  = *(const float4*)&t1s[e + i][w0 + 8];
        *(float4*)&win[12] = *(const float4*)&t1s[e + i][w0 + 12];
#pragma unroll
        for (int j = 0; j < 9; ++j) {
          float wv = w3[i * 9 + j];
#pragma unroll
          for (int k = 0; k < 8; ++k) o[k] += win[j + k] * wv;
        }
      }
      unsigned short ob[8];
#pragma unroll
      for (int k = 0; k < 8; ++k) ob[k] = to_bf16(o[k]);
      const int row = e + 2;
      char* dst = (char*)t3s + ((q * 36 + row) * 72) * 2 + ((wq ^ (row & 7)) * 16);
      *(uint4*)dst = *(const uint4*)ob;
    }
  }
  __syncthreads();
  // ---- t4: (5,1) grouped conv along e over the 4 staged channels
#pragma unroll
  for (int qo = 0; qo < 4; ++qo) {
    const int ch = c0 + qo;
    const float* w4 = p4 + ch * 20;
    float acc[8];
#pragma unroll
    for (int k = 0; k < 8; ++k) acc[k] = 0.f;
#pragma unroll
    for (int ci = 0; ci < 4; ++ci) {
#pragma unroll
      for (int u = 0; u < 5; ++u) {
        const int row = e + u;  // true e+u-2, stored +2
        const char* src = (const char*)t3s + ((ci * 36 + row) * 72) * 2 + ((wq ^ (row & 7)) * 16);
        uint4 v = *(const uint4*)src;
        const unsigned short* vs = (const unsigned short*)&v;
        float wv = w4[ci * 5 + u];
#pragma unroll
        for (int k = 0; k < 8; ++k) acc[k] += from_bf16(vs[k]) * wv;
      }
    }
    unsigned short ob[8];
#pragma unroll
    for (int k = 0; k < 8; ++k) ob[k] = to_bf16(acc[k]);
    *(uint4*)(t4b + ((size_t)(n * C + ch)) * (E * W) + e * 64 + w0) = *(const uint4*)ob;
  }
}

// ---------------------------------------------------------------------------
// p5 [2048][768] f32 -> p5t [768][2048] bf16 (transpose + convert)
// ---------------------------------------------------------------------------
__global__ __launch_bounds__(256) void k_p5t(const float* __restrict__ p5,
                                             unsigned short* __restrict__ p5t) {
  const int f0 = blockIdx.x * 64;
  const int k0 = blockIdx.y * 64;
  const int tid = threadIdx.x;
  __shared__ __align__(16) unsigned short ls[64][264];
  int fl = tid & 63, k4 = tid >> 6;
  for (int i = 0; i < 16; ++i) {
    int kl = k4 * 16 + i;
    ls[fl][kl] = to_bf16(p5[(size_t)(k0 + kl) * F + f0 + fl]);
  }
  __syncthreads();
#pragma unroll
  for (int j = 0; j < 2; ++j) {
    int chunk = tid + 256 * j;
    int row = chunk >> 3, slot = chunk & 7;
    *(uint4*)(p5t + (size_t)(f0 + row) * K5 + k0 + slot * 8) = *(const uint4*)&ls[row][slot * 8];
  }
}

// ---------------------------------------------------------------------------
// x [n][c][h][w] f32 -> xt [n][64 + h*64+w + 64][c] bf16, zero pads
// ---------------------------------------------------------------------------
__global__ __launch_bounds__(256) void k_xt(const float* __restrict__ x,
                                            unsigned short* __restrict__ xt) {
  const int hi = blockIdx.x;   // 0..65
  const int n = blockIdx.y;
  const int tid = threadIdx.x;
  unsigned short* dst = xt + ((size_t)n * XROWS + hi * 64) * C;
  if (hi == 0 || hi == 65) {
    uint4 z = make_uint4(0, 0, 0, 0);
    uint4* d4 = (uint4*)dst;
#pragma unroll
    for (int i = 0; i < 8; ++i) d4[tid + 256 * i] = z;
    return;
  }
  const int h = hi - 1;
  __shared__ __align__(16) unsigned short ls[64][264];
  const float* xp = x + ((size_t)n * C) * HW + h * 64;
  int w = tid & 63, c4 = tid >> 6;
  for (int i = 0; i < 64; ++i) {
    int c = c4 * 64 + i;
    ls[w][c] = to_bf16(xp[(size_t)c * HW + w]);
  }
  __syncthreads();
#pragma unroll
  for (int j = 0; j < 8; ++j) {
    int chunk = tid + 256 * j;          // 2048 chunks of 16B
    int row = chunk >> 5, slot = chunk & 31;
    *(uint4*)(dst + row * C + slot * 8) = *(const uint4*)&ls[row][slot * 8];
  }
}

// ---------------------------------------------------------------------------
// k_t5m: t5[4096][768] f32 = t4b[4096][2048]bf16 x p5t^T  (MFMA 128x128 tile)
// ---------------------------------------------------------------------------
__global__ __launch_bounds__(256) void k_t5m(const unsigned short* __restrict__ A,
                                             const unsigned short* __restrict__ Bt,
                                             float* __restrict__ Cout) {
  const int n0 = blockIdx.x * 128;
  const int m0 = blockIdx.y * 128;
  const int tid = threadIdx.x;
  const int lane = tid & 63;
  const int wave = tid >> 6;
  const int wm = wave >> 1, wn = wave & 1;
  __shared__ __align__(16) short As[8192];
  __shared__ __align__(16) short Bs[8192];
  f32x4 acc[4][4] = {};
  const int lr = lane >> 3;
  const int ls = lane & 7;

  for (int k0 = 0; k0 < K5; k0 += 64) {
#pragma unroll
    for (int i = 0; i < 4; ++i) {
      int inst = wave * 4 + i;
      int r = inst * 8 + lr;
      int sw = ls ^ (r & 7);
      gload16((const char*)(A + (size_t)(m0 + r) * K5 + k0) + sw * 16,
              (char*)As + inst * 1024);
      gload16((const char*)(Bt + (size_t)(n0 + r) * K5 + k0) + sw * 16,
              (char*)Bs + inst * 1024);
    }
    __syncthreads();
#pragma unroll
    for (int kh = 0; kh < 2; ++kh) {
      s16x8 af[4], bf[4];
#pragma unroll
      for (int mi = 0; mi < 4; ++mi) {
        int row = wm * 64 + mi * 16 + (lane & 15);
        int byte = (row * 128 + kh * 64 + (lane >> 4) * 16) ^ ((row & 7) << 4);
        af[mi] = *(const s16x8*)((const char*)As + byte);
      }
#pragma unroll
      for (int ni = 0; ni < 4; ++ni) {
        int row = wn * 64 + ni * 16 + (lane & 15);
        int byte = (row * 128 + kh * 64 + (lane >> 4) * 16) ^ ((row & 7) << 4);
        bf[ni] = *(const s16x8*)((const char*)Bs + byte);
      }
#pragma unroll
      for (int mi = 0; mi < 4; ++mi)
#pragma unroll
        for (int ni = 0; ni < 4; ++ni)
          acc[mi][ni] = __builtin_amdgcn_mfma_f32_16x16x32_bf16(af[mi], bf[ni], acc[mi][ni], 0, 0, 0);
    }
    __syncthreads();
  }
#pragma unroll
  for (int mi = 0; mi < 4; ++mi) {
    int rbase = m0 + wm * 64 + mi * 16 + (lane >> 4) * 4;
#pragma unroll
    for (int ni = 0; ni < 4; ++ni) {
      int col = n0 + wn * 64 + ni * 16 + (lane & 15);
#pragma unroll
      for (int q = 0; q < 4; ++q)
        Cout[(size_t)(rbase + q) * F + col] = acc[mi][ni][q];
    }
  }
}

// ---------------------------------------------------------------------------
// k_t6: t5 f32 -> 3-tap dw conv (original f order) -> scale -> bf16 in f' order
// f' = kk*256 + c2  (f = 3*c2 + kk)
// ---------------------------------------------------------------------------
__global__ __launch_bounds__(256) void k_t6(const float* __restrict__ t5,
                                            const float* __restrict__ p6,
                                            unsigned short* __restrict__ t6b) {
  int idx = blockIdx.x * 256 + threadIdx.x;
  if (idx >= NB * C * F) return;
  int fp = idx % F;
  int nc = idx / F;
  int c = nc & 255;
  int c2 = fp & 255;
  int kk = fp >> 8;
  int f = 3 * c2 + kk;
  const float* row = t5 + (size_t)nc * F;
  const float* wt = p6 + c * 3;
  float acc = row[f] * wt[1];
  if (f > 0) acc += row[f - 1] * wt[0];
  if (f < F - 1) acc += row[f + 1] * wt[2];
  t6b[idx] = to_bf16(acc * 0.03608439182435161f);
}

// ---------------------------------------------------------------------------
// k_outm: out[n][256][4096] f32 = t6b[n][256][768] x B' (from xt, shifted rows)
// ---------------------------------------------------------------------------
__global__ __launch_bounds__(256) void k_outm(const unsigned short* __restrict__ t6b,
                                              const unsigned short* __restrict__ xt,
                                              float* __restrict__ outp) {
  const int p0 = blockIdx.x * 128;   // 32
  const int m0 = blockIdx.y * 128;   // 2
  const int n  = blockIdx.z;         // 16
  const int tid = threadIdx.x;
  const int lane = tid & 63;
  const int wave = tid >> 6;
  const int wm = wave >> 1, wn = wave & 1;
  __shared__ __align__(16) short As[8192];
  __shared__ __align__(16) short Bs[8192];
  f32x4 acc[4][4] = {};
  const int lr = lane >> 3;
  const int ls = lane & 7;
  const unsigned short* Abase = t6b + (size_t)(n * C) * F;
  const unsigned short* Xbase = xt + (size_t)n * XROWS * C;

  for (int kt = 0; kt < 12; ++kt) {
    int k0 = kt * 64;
    int kk = k0 >> 8;
    int c20 = k0 & 255;
#pragma unroll
    for (int i = 0; i < 4; ++i) {
      int inst = wave * 4 + i;
      int r = inst * 8 + lr;
      int sw = ls ^ (r & 7);
      gload16((const char*)(Abase + (size_t)(m0 + r) * F + k0) + sw * 16,
              (char*)As + inst * 1024);
      gload16((const char*)(Xbase + (size_t)(p0 + r + (kk << 6)) * C + c20) + sw * 16,
              (char*)Bs + inst * 1024);
    }
    __syncthreads();
#pragma unroll
    for (int kh = 0; kh < 2; ++kh) {
      s16x8 af[4], bf[4];
#pragma unroll
      for (int mi = 0; mi < 4; ++mi) {
        int row = wm * 64 + mi * 16 + (lane & 15);
        int byte = (row * 128 + kh * 64 + (lane >> 4) * 16) ^ ((row & 7) << 4);
        af[mi] = *(const s16x8*)((const char*)As + byte);
      }
#pragma unroll
      for (int ni = 0; ni < 4; ++ni) {
        int row = wn * 64 + ni * 16 + (lane & 15);
        int byte = (row * 128 + kh * 64 + (lane >> 4) * 16) ^ ((row & 7) << 4);
        bf[ni] = *(const s16x8*)((const char*)Bs + byte);
      }
#pragma unroll
      for (int mi = 0; mi < 4; ++mi)
#pragma unroll
        for (int ni = 0; ni < 4; ++ni)
          acc[mi][ni] = __builtin_amdgcn_mfma_f32_16x16x32_bf16(af[mi], bf[ni], acc[mi][ni], 0, 0, 0);
    }
    __syncthreads();
  }
  float* obase = outp + (size_t)(n * C) * HW;
#pragma unroll
  for (int mi = 0; mi < 4; ++mi) {
    int rbase = m0 + wm * 64 + mi * 16 + (lane >> 4) * 4;
#pragma unroll
    for (int ni = 0; ni < 4; ++ni) {
      int col = p0 + wn * 64 + ni * 16 + (lane & 15);
#pragma unroll
      for (int q = 0; q < 4; ++q)
        obase[(size_t)(rbase + q) * HW + col] = acc[mi][ni][q];
    }
  }
}

extern "C" void kernel_launch(void* const* d_in, const int* in_sizes, int n_in,
                              void* d_out, int out_size, void* d_ws, size_t ws_size,
                              hipStream_t stream) {
  (void)in_sizes; (void)n_in; (void)out_size; (void)ws_size;
  const float* x  = (const float*)d_in[0];
  const float* p1 = (const float*)d_in[1];
  const float* p3 = (const float*)d_in[2];
  const float* p4 = (const float*)d_in[3];
  const float* p5 = (const float*)d_in[4];
  const float* p6 = (const float*)d_in[5];
  float* out = (float*)d_out;

  char* ws = (char*)d_ws;
  // region [0, 34.6MB): early = {t4b, p5t, t5}; late (after k_t6) = xt
  unsigned short* t4b = (unsigned short*)ws;                          // 16.8 MB
  unsigned short* p5t = (unsigned short*)(ws + 16777216);             //  3.1 MB
  float*          t5  = (float*)(ws + 19922944);                      // 12.6 MB
  unsigned short* xt  = (unsigned short*)ws;                          // 34.6 MB (overlays t4b/p5t/t5)
  unsigned short* t6b = (unsigned short*)(ws + 34603008);             //  6.3 MB

  k_t4 <<<dim3(NB * 64), 256, 0, stream>>>(x, p1, p3, p4, t4b);
  k_p5t<<<dim3(12, 32), 256, 0, stream>>>(p5, p5t);
  k_t5m<<<dim3(6, 32), 256, 0, stream>>>(t4b, p5t, t5);
  k_t6 <<<dim3((NB * C * F + 255) / 256), 256, 0, stream>>>(t5, p6, t6b);
  k_xt <<<dim3(66, NB), 256, 0, stream>>>(x, xt);
  k_outm<<<dim3(32, 2, NB), 256, 0, stream>>>(t6b, xt, out);
}

// Round 4
// 194.577 us; speedup vs baseline: 5.0275x; 1.0073x over previous
//
#include <hip/hip_runtime.h>

#define NB 16
#define C  256
#define H  64
#define W  64
#define E  32
#define F  768
#define HW 4096
#define K5 2048
#define XROWS 4224   // 64 pad + 4096 + 64 pad

typedef __attribute__((ext_vector_type(4))) float f32x4;
typedef __attribute__((ext_vector_type(8))) short s16x8;

__device__ inline unsigned short to_bf16(float f) {
  union { float f; unsigned u; } v; v.f = f;
  unsigned u = v.u;
  u += 0x7fff + ((u >> 16) & 1);
  return (unsigned short)(u >> 16);
}

__device__ inline float from_bf16(unsigned short s) {
  union { unsigned u; float f; } v; v.u = ((unsigned)s) << 16;
  return v.f;
}

__device__ inline void gload16(const void* g, void* l) {
  __builtin_amdgcn_global_load_lds((const __attribute__((address_space(1))) unsigned int*)g,
                                   (__attribute__((address_space(3))) unsigned int*)l, 16, 0, 0);
}

// ---------------------------------------------------------------------------
// Kernel A: fused t1 -> t3 (9x9 dw) -> t4 (5x1 grouped), output bf16.
// All-bf16 LDS staging: 31.6 KB -> 4 blocks/CU co-resident (1024 blocks total,
// exactly 4/CU of work -> single-round residency). Balanced bank patterns:
// t1s rows 144 B (natural +4-bank/row rotation), t3s slot-XOR swizzle.
// ---------------------------------------------------------------------------
__global__ __launch_bounds__(256, 4) void k_t4(const float* __restrict__ x,
                                               const float* __restrict__ p1,
                                               const float* __restrict__ p3,
                                               const float* __restrict__ p4,
                                               unsigned short* __restrict__ t4b) {
  const int n  = blockIdx.x >> 6;
  const int g  = blockIdx.x & 63;
  const int c0 = g * 4;
  const int tid = threadIdx.x;

  __shared__ __align__(16) unsigned short xs[64][64];     //  8192 B
  __shared__ __align__(16) unsigned short t1s[40][72];    //  5760 B (pad 4 rows/cols each side)
  __shared__ __align__(16) unsigned short t3s[4][36][64]; // 18432 B (pad 2 rows each side, XOR swz)

  // zero once: pads stay zero, interiors fully rewritten per q
  {
    unsigned* u = (unsigned*)&t1s[0][0];
    for (int i = tid; i < (40 * 72) / 2; i += 256) u[i] = 0u;
    unsigned* v = (unsigned*)&t3s[0][0][0];
    for (int i = tid; i < (4 * 36 * 64) / 2; i += 256) v[i] = 0u;
  }

  const int w  = tid & 63;                                   // t1 mapping
  const int e0 = __builtin_amdgcn_readfirstlane(tid >> 6);   // wave-uniform
  const int e  = tid >> 3;                                   // t3/t4 mapping: 0..31
  const int wq = tid & 7;

  for (int q = 0; q < 4; ++q) {
    const int ch = c0 + q;
    const float* xp = x + ((size_t)(n * C + ch)) * HW;
    __syncthreads();
    // ---- stage x as bf16
#pragma unroll
    for (int i = 0; i < 4; ++i) {
      float4 v = ((const float4*)xp)[tid + 256 * i];
      unsigned short b[4] = {to_bf16(v.x), to_bf16(v.y), to_bf16(v.z), to_bf16(v.w)};
      *(uint2*)((unsigned short*)xs + 4 * (tid + 256 * i)) = *(const uint2*)b;
    }
    __syncthreads();
    // ---- t1: t1s[4+e][4+w] = sum_h xs[h][w] * p1[h][e], e = e0 + 4i
    {
      float acc[8];
#pragma unroll
      for (int i = 0; i < 8; ++i) acc[i] = 0.f;
      for (int h = 0; h < 64; ++h) {
        float xv = from_bf16(xs[h][w]);
        const float* p1h = p1 + h * 32 + e0;
#pragma unroll
        for (int i = 0; i < 8; ++i) acc[i] += xv * p1h[4 * i];
      }
#pragma unroll
      for (int i = 0; i < 8; ++i) t1s[4 + e0 + 4 * i][4 + w] = to_bf16(acc[i]);
    }
    __syncthreads();
    // ---- t3: 9x9 depthwise, branch-free, 16-bf16 register window per row
    {
      const float* w3 = p3 + ch * 81;
      float o[8];
#pragma unroll
      for (int k = 0; k < 8; ++k) o[k] = 0.f;
#pragma unroll
      for (int i = 0; i < 9; ++i) {
        uint4 wv0 = *(const uint4*)((const char*)t1s + 144 * (e + i) + 16 * wq);
        uint4 wv1 = *(const uint4*)((const char*)t1s + 144 * (e + i) + 16 * wq + 16);
        const unsigned short* ws0 = (const unsigned short*)&wv0;
        const unsigned short* ws1 = (const unsigned short*)&wv1;
        float win[16];
#pragma unroll
        for (int k = 0; k < 8; ++k) { win[k] = from_bf16(ws0[k]); win[8 + k] = from_bf16(ws1[k]); }
#pragma unroll
        for (int j = 0; j < 9; ++j) {
          float wt = w3[i * 9 + j];
#pragma unroll
          for (int k = 0; k < 8; ++k) o[k] += win[j + k] * wt;
        }
      }
      unsigned short ob[8];
#pragma unroll
      for (int k = 0; k < 8; ++k) ob[k] = to_bf16(o[k]);
      const int row = e + 2;
      char* dst = (char*)t3s + 128 * (q * 36 + row) + 16 * (wq ^ (row & 7));
      *(uint4*)dst = *(const uint4*)ob;
    }
  }
  __syncthreads();
  // ---- t4: (5,1) grouped conv; each t3 read shared across the 4 out-channels
  {
    float acc[4][8];
#pragma unroll
    for (int qo = 0; qo < 4; ++qo)
#pragma unroll
      for (int k = 0; k < 8; ++k) acc[qo][k] = 0.f;
#pragma unroll
    for (int ci = 0; ci < 4; ++ci) {
#pragma unroll
      for (int u = 0; u < 5; ++u) {
        const int row = e + u;  // true e+u-2, stored +2
        const char* src = (const char*)t3s + 128 * (ci * 36 + row) + 16 * (wq ^ (row & 7));
        uint4 v = *(const uint4*)src;
        const unsigned short* vs = (const unsigned short*)&v;
        float vf[8];
#pragma unroll
        for (int k = 0; k < 8; ++k) vf[k] = from_bf16(vs[k]);
#pragma unroll
        for (int qo = 0; qo < 4; ++qo) {
          float wv = p4[(c0 + qo) * 20 + ci * 5 + u];
#pragma unroll
          for (int k = 0; k < 8; ++k) acc[qo][k] += vf[k] * wv;
        }
      }
    }
#pragma unroll
    for (int qo = 0; qo < 4; ++qo) {
      unsigned short ob[8];
#pragma unroll
      for (int k = 0; k < 8; ++k) ob[k] = to_bf16(acc[qo][k]);
      *(uint4*)(t4b + ((size_t)(n * C + c0 + qo)) * (E * W) + e * 64 + wq * 8) = *(const uint4*)ob;
    }
  }
}

// ---------------------------------------------------------------------------
// p5 [2048][768] f32 -> p5t [768][2048] bf16 (transpose + convert)
// ---------------------------------------------------------------------------
__global__ __launch_bounds__(256) void k_p5t(const float* __restrict__ p5,
                                             unsigned short* __restrict__ p5t) {
  const int f0 = blockIdx.x * 64;
  const int k0 = blockIdx.y * 64;
  const int tid = threadIdx.x;
  __shared__ __align__(16) unsigned short ls[64][264];
  int fl = tid & 63, k4 = tid >> 6;
  for (int i = 0; i < 16; ++i) {
    int kl = k4 * 16 + i;
    ls[fl][kl] = to_bf16(p5[(size_t)(k0 + kl) * F + f0 + fl]);
  }
  __syncthreads();
#pragma unroll
  for (int j = 0; j < 2; ++j) {
    int chunk = tid + 256 * j;
    int row = chunk >> 3, slot = chunk & 7;
    *(uint4*)(p5t + (size_t)(f0 + row) * K5 + k0 + slot * 8) = *(const uint4*)&ls[row][slot * 8];
  }
}

// ---------------------------------------------------------------------------
// x [n][c][h][w] f32 -> xt [n][64 + h*64+w + 64][c] bf16, zero pads
// ---------------------------------------------------------------------------
__global__ __launch_bounds__(256) void k_xt(const float* __restrict__ x,
                                            unsigned short* __restrict__ xt) {
  const int hi = blockIdx.x;   // 0..65
  const int n = blockIdx.y;
  const int tid = threadIdx.x;
  unsigned short* dst = xt + ((size_t)n * XROWS + hi * 64) * C;
  if (hi == 0 || hi == 65) {
    uint4 z = make_uint4(0, 0, 0, 0);
    uint4* d4 = (uint4*)dst;
#pragma unroll
    for (int i = 0; i < 8; ++i) d4[tid + 256 * i] = z;
    return;
  }
  const int h = hi - 1;
  __shared__ __align__(16) unsigned short ls[64][264];
  const float* xp = x + ((size_t)n * C) * HW + h * 64;
  int w = tid & 63, c4 = tid >> 6;
  for (int i = 0; i < 64; ++i) {
    int c = c4 * 64 + i;
    ls[w][c] = to_bf16(xp[(size_t)c * HW + w]);
  }
  __syncthreads();
#pragma unroll
  for (int j = 0; j < 8; ++j) {
    int chunk = tid + 256 * j;          // 2048 chunks of 16B
    int row = chunk >> 5, slot = chunk & 31;
    *(uint4*)(dst + row * C + slot * 8) = *(const uint4*)&ls[row][slot * 8];
  }
}

// ---------------------------------------------------------------------------
// k_t5m: t5[4096][768] f32 = t4b[4096][2048]bf16 x p5t^T  (MFMA 128x128 tile)
// ---------------------------------------------------------------------------
__global__ __launch_bounds__(256) void k_t5m(const unsigned short* __restrict__ A,
                                             const unsigned short* __restrict__ Bt,
                                             float* __restrict__ Cout) {
  const int n0 = blockIdx.x * 128;
  const int m0 = blockIdx.y * 128;
  const int tid = threadIdx.x;
  const int lane = tid & 63;
  const int wave = tid >> 6;
  const int wm = wave >> 1, wn = wave & 1;
  __shared__ __align__(16) short As[8192];
  __shared__ __align__(16) short Bs[8192];
  f32x4 acc[4][4] = {};
  const int lr = lane >> 3;
  const int ls = lane & 7;

  for (int k0 = 0; k0 < K5; k0 += 64) {
#pragma unroll
    for (int i = 0; i < 4; ++i) {
      int inst = wave * 4 + i;
      int r = inst * 8 + lr;
      int sw = ls ^ (r & 7);
      gload16((const char*)(A + (size_t)(m0 + r) * K5 + k0) + sw * 16,
              (char*)As + inst * 1024);
      gload16((const char*)(Bt + (size_t)(n0 + r) * K5 + k0) + sw * 16,
              (char*)Bs + inst * 1024);
    }
    __syncthreads();
#pragma unroll
    for (int kh = 0; kh < 2; ++kh) {
      s16x8 af[4], bf[4];
#pragma unroll
      for (int mi = 0; mi < 4; ++mi) {
        int row = wm * 64 + mi * 16 + (lane & 15);
        int byte = (row * 128 + kh * 64 + (lane >> 4) * 16) ^ ((row & 7) << 4);
        af[mi] = *(const s16x8*)((const char*)As + byte);
      }
#pragma unroll
      for (int ni = 0; ni < 4; ++ni) {
        int row = wn * 64 + ni * 16 + (lane & 15);
        int byte = (row * 128 + kh * 64 + (lane >> 4) * 16) ^ ((row & 7) << 4);
        bf[ni] = *(const s16x8*)((const char*)Bs + byte);
      }
#pragma unroll
      for (int mi = 0; mi < 4; ++mi)
#pragma unroll
        for (int ni = 0; ni < 4; ++ni)
          acc[mi][ni] = __builtin_amdgcn_mfma_f32_16x16x32_bf16(af[mi], bf[ni], acc[mi][ni], 0, 0, 0);
    }
    __syncthreads();
  }
#pragma unroll
  for (int mi = 0; mi < 4; ++mi) {
    int rbase = m0 + wm * 64 + mi * 16 + (lane >> 4) * 4;
#pragma unroll
    for (int ni = 0; ni < 4; ++ni) {
      int col = n0 + wn * 64 + ni * 16 + (lane & 15);
#pragma unroll
      for (int q = 0; q < 4; ++q)
        Cout[(size_t)(rbase + q) * F + col] = acc[mi][ni][q];
    }
  }
}

// ---------------------------------------------------------------------------
// k_t6: t5 f32 -> 3-tap dw conv (original f order) -> scale -> bf16 in f' order
// f' = kk*256 + c2  (f = 3*c2 + kk)
// ---------------------------------------------------------------------------
__global__ __launch_bounds__(256) void k_t6(const float* __restrict__ t5,
                                            const float* __restrict__ p6,
                                            unsigned short* __restrict__ t6b) {
  int idx = blockIdx.x * 256 + threadIdx.x;
  if (idx >= NB * C * F) return;
  int fp = idx % F;
  int nc = idx / F;
  int c = nc & 255;
  int c2 = fp & 255;
  int kk = fp >> 8;
  int f = 3 * c2 + kk;
  const float* row = t5 + (size_t)nc * F;
  const float* wt = p6 + c * 3;
  float acc = row[f] * wt[1];
  if (f > 0) acc += row[f - 1] * wt[0];
  if (f < F - 1) acc += row[f + 1] * wt[2];
  t6b[idx] = to_bf16(acc * 0.03608439182435161f);
}

// ---------------------------------------------------------------------------
// k_outm: out[n][256][4096] f32 = t6b[n][256][768] x B' (from xt, shifted rows)
// ---------------------------------------------------------------------------
__global__ __launch_bounds__(256) void k_outm(const unsigned short* __restrict__ t6b,
                                              const unsigned short* __restrict__ xt,
                                              float* __restrict__ outp) {
  const int p0 = blockIdx.x * 128;   // 32
  const int m0 = blockIdx.y * 128;   // 2
  const int n  = blockIdx.z;         // 16
  const int tid = threadIdx.x;
  const int lane = tid & 63;
  const int wave = tid >> 6;
  const int wm = wave >> 1, wn = wave & 1;
  __shared__ __align__(16) short As[8192];
  __shared__ __align__(16) short Bs[8192];
  f32x4 acc[4][4] = {};
  const int lr = lane >> 3;
  const int ls = lane & 7;
  const unsigned short* Abase = t6b + (size_t)(n * C) * F;
  const unsigned short* Xbase = xt + (size_t)n * XROWS * C;

  for (int kt = 0; kt < 12; ++kt) {
    int k0 = kt * 64;
    int kk = k0 >> 8;
    int c20 = k0 & 255;
#pragma unroll
    for (int i = 0; i < 4; ++i) {
      int inst = wave * 4 + i;
      int r = inst * 8 + lr;
      int sw = ls ^ (r & 7);
      gload16((const char*)(Abase + (size_t)(m0 + r) * F + k0) + sw * 16,
              (char*)As + inst * 1024);
      gload16((const char*)(Xbase + (size_t)(p0 + r + (kk << 6)) * C + c20) + sw * 16,
              (char*)Bs + inst * 1024);
    }
    __syncthreads();
#pragma unroll
    for (int kh = 0; kh < 2; ++kh) {
      s16x8 af[4], bf[4];
#pragma unroll
      for (int mi = 0; mi < 4; ++mi) {
        int row = wm * 64 + mi * 16 + (lane & 15);
        int byte = (row * 128 + kh * 64 + (lane >> 4) * 16) ^ ((row & 7) << 4);
        af[mi] = *(const s16x8*)((const char*)As + byte);
      }
#pragma unroll
      for (int ni = 0; ni < 4; ++ni) {
        int row = wn * 64 + ni * 16 + (lane & 15);
        int byte = (row * 128 + kh * 64 + (lane >> 4) * 16) ^ ((row & 7) << 4);
        bf[ni] = *(const s16x8*)((const char*)Bs + byte);
      }
#pragma unroll
      for (int mi = 0; mi < 4; ++mi)
#pragma unroll
        for (int ni = 0; ni < 4; ++ni)
          acc[mi][ni] = __builtin_amdgcn_mfma_f32_16x16x32_bf16(af[mi], bf[ni], acc[mi][ni], 0, 0, 0);
    }
    __syncthreads();
  }
  float* obase = outp + (size_t)(n * C) * HW;
#pragma unroll
  for (int mi = 0; mi < 4; ++mi) {
    int rbase = m0 + wm * 64 + mi * 16 + (lane >> 4) * 4;
#pragma unroll
    for (int ni = 0; ni < 4; ++ni) {
      int col = p0 + wn * 64 + ni * 16 + (lane & 15);
#pragma unroll
      for (int q = 0; q < 4; ++q)
        obase[(size_t)(rbase + q) * HW + col] = acc[mi][ni][q];
    }
  }
}

extern "C" void kernel_launch(void* const* d_in, const int* in_sizes, int n_in,
                              void* d_out, int out_size, void* d_ws, size_t ws_size,
                              hipStream_t stream) {
  (void)in_sizes; (void)n_in; (void)out_size; (void)ws_size;
  const float* x  = (const float*)d_in[0];
  const float* p1 = (const float*)d_in[1];
  const float* p3 = (const float*)d_in[2];
  const float* p4 = (const float*)d_in[3];
  const float* p5 = (const float*)d_in[4];
  const float* p6 = (const float*)d_in[5];
  float* out = (float*)d_out;

  char* ws = (char*)d_ws;
  // region [0, 34.6MB): early = {t4b, p5t, t5}; late (after k_t6) = xt
  unsigned short* t4b = (unsigned short*)ws;                          // 16.8 MB
  unsigned short* p5t = (unsigned short*)(ws + 16777216);             //  3.1 MB
  float*          t5  = (float*)(ws + 19922944);                      // 12.6 MB
  unsigned short* xt  = (unsigned short*)ws;                          // 34.6 MB (overlays t4b/p5t/t5)
  unsigned short* t6b = (unsigned short*)(ws + 34603008);             //  6.3 MB

  k_t4 <<<dim3(NB * 64), 256, 0, stream>>>(x, p1, p3, p4, t4b);
  k_p5t<<<dim3(12, 32), 256, 0, stream>>>(p5, p5t);
  k_t5m<<<dim3(6, 32), 256, 0, stream>>>(t4b, p5t, t5);
  k_t6 <<<dim3((NB * C * F + 255) / 256), 256, 0, stream>>>(t5, p6, t6b);
  k_xt <<<dim3(66, NB), 256, 0, stream>>>(x, xt);
  k_outm<<<dim3(32, 2, NB), 256, 0, stream>>>(t6b, xt, out);
}